// Round 17
// baseline (116.375 us; speedup 1.0000x reference)
//
#include <hip/hip_runtime.h>
#include <hip/hip_bf16.h>
#include <cstdint>
#include <cstddef>

#define BATCH 8
#define CINC  64
#define HH    128
#define WWW   128
#define COUTC 128
#define KKC   9
#define KDIM  576
#define HWC   (HH*WWW)      // 16384
#define NPX   (BATCH*HWC)   // 131072

#define WIN_W 64
#define LDS_SZ (6*WIN_W*128)   // 49152 B -> 3 blocks/CU

typedef float f32x4 __attribute__((ext_vector_type(4)));
typedef short bf16x8 __attribute__((ext_vector_type(8)));

static __device__ __forceinline__ unsigned short f2bf(float f){
    unsigned u = __builtin_bit_cast(unsigned, f);
    u += 0x7fffu + ((u >> 16) & 1u);
    return (unsigned short)(u >> 16);
}
static __device__ __forceinline__ float bf_lo(unsigned u){
    return __builtin_bit_cast(float, u << 16);
}
static __device__ __forceinline__ float bf_hi(unsigned u){
    return __builtin_bit_cast(float, u & 0xffff0000u);
}
static __device__ __forceinline__ unsigned cvtpk(float lo, float hi){
    unsigned r;
    asm("v_cvt_pk_bf16_f32 %0, %1, %2" : "=v"(r) : "v"(lo), "v"(hi));
    return r;
}

// butterfly slot for value o after the 2-step xor16/xor32 redistribution
#define IDX(o) (16*((((o)&15)>>2)>>1) + 8*((((o)&15)>>2)&1) + 4*((o)>>4) + ((o)&3))

// ---- K0: pack weights -------------------------------------------------------
// Wb2: [kk][s][cog0..7] 1KB chunks (lane L: o=cog*16+(L&15), c=32s+8*(L>>4)+j)
// Wc3 (SWAPPED offset-conv A-operand): [kk][s][t] 1KB chunks
//      (lane L: o=16t+(L&15), c=32s+8*(L>>4)+j; o>=27 -> 0)
// Wp2: [s][fn0..3] for conv1x1.
__global__ __launch_bounds__(256) void prep_weights(
        const float* __restrict__ off_w, const float* __restrict__ mod_w,
        const float* __restrict__ reg_w, const float* __restrict__ pre_w,
        unsigned short* __restrict__ Wb2, unsigned short* __restrict__ Wc3,
        unsigned short* __restrict__ Wp2)
{
    int idx = blockIdx.x * 256 + threadIdx.x;      // 0..96255
    if (idx < 73728) {
        int chunk = idx >> 9, within = idx & 511;
        int lane = within >> 3, j = within & 7;
        int kk = chunk >> 4, s = (chunk >> 3) & 1, cog = chunk & 7;
        int o = cog * 16 + (lane & 15);
        int c = 32*s + 8*(lane >> 4) + j;
        Wb2[idx] = f2bf(reg_w[(o * CINC + c) * KKC + kk]);
    }
    int idx2 = idx - 73728;
    if (idx2 >= 0 && idx2 < 18432) {
        int chunk = idx2 >> 9, within = idx2 & 511;
        int lane = within >> 3, j = within & 7;
        int kk = chunk >> 2, s = (chunk >> 1) & 1, t = chunk & 1;
        int o = 16*t + (lane & 15);
        int c = 32*s + 8*(lane >> 4) + j;
        float v = 0.f;
        if (o < 18)      v = off_w[(o * CINC + c) * KKC + kk];
        else if (o < 27) v = mod_w[((o - 18) * CINC + c) * KKC + kk];
        Wc3[idx2] = f2bf(v);
    }
    int idx3 = idx - 92160;
    if (idx3 >= 0 && idx3 < 4096) {
        int chunk = idx3 >> 9, within = idx3 & 511;
        int lane = within >> 3, j = within & 7;
        int s = chunk >> 2, fn = chunk & 3;
        int o = fn * 16 + (lane & 15);
        int c = 32*s + 8*(lane >> 4) + j;
        Wp2[idx3] = f2bf(pre_w[o * CINC + c]);
    }
}

// ---- K1: 1x1 conv via MFMA, NCHW f32 -> NHWC bf16 (unchanged) ---------------
__global__ __launch_bounds__(256) void conv1x1(
        const float* __restrict__ x, const unsigned short* __restrict__ Wp2,
        const float* __restrict__ pre_b, unsigned short* __restrict__ xp)
{
    __shared__ unsigned short slab[4][64 * 72];

    const int tid = threadIdx.x;
    const int lane = tid & 63;
    const int wv   = tid >> 6;
    const int l15  = lane & 15;
    const int l4   = lane >> 4;

    int bid = (int)blockIdx.x;
    int bswz = (bid & 7) * 64 + (bid >> 3);
    int pxb = bswz * 256 + wv * 64;
    int b = pxb >> 14, hw0 = pxb & 16383;
    const float* xb = x + (size_t)b * CINC * HWC + hw0;

    bf16x8 bw[4][2];
    #pragma unroll
    for (int fn = 0; fn < 4; ++fn)
        #pragma unroll
        for (int s = 0; s < 2; ++s)
            bw[fn][s] = *(const bf16x8*)(Wp2 + (size_t)(s*4 + fn) * 512 + lane * 8);
    float pb[4];
    #pragma unroll
    for (int fn = 0; fn < 4; ++fn) pb[fn] = pre_b[16*fn + l15];

    f32x4 acc[4][4];
    #pragma unroll
    for (int su = 0; su < 4; ++su)
        #pragma unroll
        for (int fn = 0; fn < 4; ++fn) acc[su][fn] = (f32x4){0.f,0.f,0.f,0.f};

    #pragma unroll
    for (int su = 0; su < 4; ++su) {
        #pragma unroll
        for (int s = 0; s < 2; ++s) {
            float f[8];
            #pragma unroll
            for (int j = 0; j < 8; ++j)
                f[j] = xb[(size_t)(s*32 + 8*l4 + j) * HWC + su*16 + l15];
            unsigned pk[4];
            #pragma unroll
            for (int d = 0; d < 4; ++d) pk[d] = cvtpk(f[2*d], f[2*d+1]);
            bf16x8 A = __builtin_bit_cast(bf16x8, make_uint4(pk[0], pk[1], pk[2], pk[3]));
            #pragma unroll
            for (int fn = 0; fn < 4; ++fn)
                acc[su][fn] = __builtin_amdgcn_mfma_f32_16x16x32_bf16(A, bw[fn][s], acc[su][fn], 0,0,0);
        }
    }

    unsigned short* sl = slab[wv];
    #pragma unroll
    for (int su = 0; su < 4; ++su)
        #pragma unroll
        for (int fn = 0; fn < 4; ++fn)
            #pragma unroll
            for (int r = 0; r < 4; ++r)
                sl[(su*16 + 4*l4 + r) * 72 + 16*fn + l15] = f2bf(acc[su][fn][r] + pb[fn]);
    const uint4* srow = (const uint4*)(sl + lane * 72);
    uint4* drow = (uint4*)(xp + (size_t)(pxb + lane) * 64);
    #pragma unroll
    for (int q = 0; q < 8; ++q) drow[q] = srow[q];
}

// ---- K3: fused; 3 blocks/CU; swapped Phase O + shfl butterfly; reg coords ---
// 1024 blocks x 256 thr (4 waves). Block = 2 rows x 64 px. LDS = 49,152 B
// (window only) => 3 blocks/CU = 12 waves/CU = 3 waves/SIMD.
// Wave (wv): row hrow = wv>>1, x-local slice 32*(wv&1).. (+32). Block px
// index p = 32*wv + 16*j + pr == 64*hrow + xloc (consistent row-major).
// Phase O computes D[o][px] via mfma(Wc3, window) so px sits on l15; a
// 2-step shfl_xor butterfly replicates each px's 27 coords across l4-groups
// into registers (no Dt LDS). Main loop = r14's register-direct lerp->MFMA,
// barrier-free; x-escapes at block edges use the rare global fallback.
__global__ __launch_bounds__(256, 3) void gather_einsum(
        const unsigned short* __restrict__ xp,
        const unsigned short* __restrict__ Wb2,
        const unsigned short* __restrict__ Wc3,
        const float* __restrict__ off_b,
        const float* __restrict__ mod_b,
        float* __restrict__ out)
{
    __shared__ char smem[LDS_SZ];
    char* winc = smem;                       // [6][64] px, 128B, swizzled
    float* epi = (float*)smem;               // overlay: [64 co][130] f32

    const int tid  = (int)threadIdx.x;
    const int lane = tid & 63;
    const int wv   = tid >> 6;       // 0..3
    const int l15  = lane & 15;
    const int l4   = lane >> 4;

    int bid = (int)blockIdx.x;
    int bswz = (bid & 7) * 128 + (bid >> 3);  // image = bid&7 (1024%8==0)
    const int b   = bswz >> 7;
    const int rem = bswz & 127;
    const int h0  = (rem >> 1) << 1;          // row pair
    const int x0w = (rem & 1) << 6;           // x half

    const unsigned short* xpb = xp + (size_t)b * HWC * CINC;

    // ---- stage window rows h0-2..h0+3, x = x0w..x0w+63, swizzled ----
    #pragma unroll
    for (int i = 0; i < 12; ++i) {
        int c = i * 256 + tid;            // 0..3071 16B-chunks
        int r = c >> 9;
        int cr = c & 511;
        int wx = cr >> 3, g = cr & 7;
        int y = h0 - 2 + r;
        uint4 v = make_uint4(0u,0u,0u,0u);
        if ((unsigned)y < 128u)
            v = *(const uint4*)(xpb + ((size_t)y * 128 + x0w + wx) * 64 + g * 8);
        *(uint4*)(winc + (r*WIN_W + wx)*128 + ((g ^ (wx & 7)) << 4)) = v;
    }
    __syncthreads();

    // ---- Phase O (swapped): D[o][px], px = l15 of each 16-px B-tile ----
    const int hrow = wv >> 1;    // wave's output row
    const int xsl  = (wv & 1) * 32;   // wave's x-local slice base
    float cy[2][9], cx[2][9], cm[2][9];
    {
        f32x4 aco[2][2];   // [j][t]
        #pragma unroll
        for (int j = 0; j < 2; ++j)
            #pragma unroll
            for (int t = 0; t < 2; ++t) aco[j][t] = (f32x4){0.f,0.f,0.f,0.f};

        #pragma unroll
        for (int kk = 0; kk < 9; ++kk) {
            bf16x8 wa[2][2];   // [s][t]
            #pragma unroll
            for (int s = 0; s < 2; ++s)
                #pragma unroll
                for (int t = 0; t < 2; ++t)
                    wa[s][t] = *(const bf16x8*)(Wc3 + (size_t)(kk*4 + s*2 + t) * 512 + lane * 8);
            int dx = kk % 3 - 1;
            int y_ = h0 + hrow + kk/3 - 1;
            bool yv = (unsigned)y_ < 128u;
            int wr_ = hrow + kk/3 + 1;
            #pragma unroll
            for (int j = 0; j < 2; ++j) {
                int gx  = x0w + xsl + 16*j + l15;   // global x of this px
                int gxx = gx + dx;
                int wx = gxx - x0w;
                bool in_win = (unsigned)wx < (unsigned)WIN_W;
                int wxc = wx < 0 ? 0 : (wx > WIN_W-1 ? WIN_W-1 : wx);
                int sx = wxc & 7;
                const char* rr = winc + (wr_*WIN_W + wxc)*128;
                uint4 b0 = *(const uint4*)(rr + ((l4 ^ sx) << 4));
                uint4 b1 = *(const uint4*)(rr + (((l4+4) ^ sx) << 4));
                if (__builtin_expect(!in_win, 0)) {
                    bool v = yv && ((unsigned)gxx < 128u);
                    const unsigned short* gp = xpb
                        + (size_t)(((y_ & 127) * 128) + (gxx & 127)) * 64 + 8*l4;
                    uint4 z = make_uint4(0u,0u,0u,0u);
                    b0 = v ? *(const uint4*)(gp)      : z;
                    b1 = v ? *(const uint4*)(gp + 32) : z;
                }
                bf16x8 B0 = __builtin_bit_cast(bf16x8, b0);
                bf16x8 B1 = __builtin_bit_cast(bf16x8, b1);
                #pragma unroll
                for (int t = 0; t < 2; ++t) {
                    aco[j][t] = __builtin_amdgcn_mfma_f32_16x16x32_bf16(wa[0][t], B0, aco[j][t], 0,0,0);
                    aco[j][t] = __builtin_amdgcn_mfma_f32_16x16x32_bf16(wa[1][t], B1, aco[j][t], 0,0,0);
                }
            }
        }

        // epilogue-O: per-value bias/base/sigmoid (o = 16t + 4*l4 + r, px = l15)
        float e0[8], e1[8];
        #pragma unroll
        for (int t = 0; t < 2; ++t)
        #pragma unroll
        for (int r = 0; r < 4; ++r) {
            int o = 16*t + 4*l4 + r;
            #pragma unroll
            for (int j = 0; j < 2; ++j) {
                float v = aco[j][t][r];
                int gx = x0w + xsl + 16*j + l15;   // global x of this px
                if (o < 18) {
                    v += off_b[o];
                    int k = o >> 1;
                    if ((o & 1) == 0) v += (float)(h0 + hrow - 1 + k/3);
                    else              v += (float)(gx - 1 + (k - (k/3)*3));
                } else if (o < 27) {
                    v = 2.f / (1.f + __expf(-(v + mod_b[o - 18])));
                }
                if (j == 0) e0[4*t + r] = v; else e1[4*t + r] = v;
            }
        }

        // butterfly: replicate all 27 values of each px across l4-groups
        const bool hb0 = (l4 & 1) != 0;
        const bool hb1 = (l4 & 2) != 0;
        #define BFLY(eA, jj) do {                                             \
            float f_[16], g_[32];                                             \
            _Pragma("unroll")                                                 \
            for (int i = 0; i < 8; ++i) {                                     \
                float p = __shfl_xor(eA[i], 16);                              \
                f_[i]   = hb0 ? p : eA[i];                                    \
                f_[8+i] = hb0 ? eA[i] : p;                                    \
            }                                                                 \
            _Pragma("unroll")                                                 \
            for (int i = 0; i < 16; ++i) {                                    \
                float p = __shfl_xor(f_[i], 32);                              \
                g_[i]    = hb1 ? p : f_[i];                                   \
                g_[16+i] = hb1 ? f_[i] : p;                                   \
            }                                                                 \
            _Pragma("unroll")                                                 \
            for (int k = 0; k < 9; ++k) {                                     \
                cy[jj][k] = g_[IDX(2*k)];                                     \
                cx[jj][k] = g_[IDX(2*k + 1)];                                 \
                cm[jj][k] = g_[IDX(18 + k)];                                  \
            }                                                                 \
        } while (0)
        BFLY(e0, 0);
        BFLY(e1, 1);
        #undef BFLY
    }
    // no barrier: coords are per-wave registers; window is read-only

    // ---- main loop: register-direct lerp -> MFMA (r14 body) ----
    f32x4 acc[2][8];
    #pragma unroll
    for (int j = 0; j < 2; ++j)
        #pragma unroll
        for (int fn = 0; fn < 8; ++fn) acc[j][fn] = (f32x4){0.f,0.f,0.f,0.f};

    #pragma unroll
    for (int kk = 0; kk < 9; ++kk) {
        bf16x8 Bs0[4], Bs1[4];
        #pragma unroll
        for (int f = 0; f < 4; ++f) {
            Bs0[f] = *(const bf16x8*)(Wb2 + (size_t)(kk*16 +      f) * 512 + lane * 8);
            Bs1[f] = *(const bf16x8*)(Wb2 + (size_t)(kk*16 +  8 + f) * 512 + lane * 8);
        }

        bf16x8 A[2][2];
        #pragma unroll
        for (int j = 0; j < 2; ++j) {
            float Y = cy[j][kk], X = cx[j][kk], M = cm[j][kk];
            float yf = floorf(Y), xf = floorf(X);
            float wy = Y - yf, wx = X - xf;
            int y0 = (int)yf, x0i = (int)xf;
            int y1 = y0 + 1, x1 = x0i + 1;
            bool yv0 = (unsigned)y0 < 128u, yv1 = (unsigned)y1 < 128u;
            bool xv0 = (unsigned)x0i < 128u, xv1 = (unsigned)x1 < 128u;
            int wr0 = y0 - (h0 - 2), wr1 = wr0 + 1;
            int wxi = x0i - x0w;
            bool inW0 = (unsigned)wxi < (unsigned)WIN_W;
            bool inW1 = (unsigned)(wxi + 1) < (unsigned)WIN_W;
            int wc0 = wr0 < 0 ? 0 : (wr0 > 5 ? 5 : wr0);
            int wc1 = wr1 < 0 ? 0 : (wr1 > 5 ? 5 : wr1);
            int wx0 = wxi < 0 ? 0 : (wxi > WIN_W-1 ? WIN_W-1 : wxi);
            int wx1 = wxi+1 < 0 ? 0 : (wxi+1 > WIN_W-1 ? WIN_W-1 : wxi+1);
            int s0 = wx0 & 7, s1 = wx1 & 7;

            const char* r00 = winc + (wc0*WIN_W + wx0)*128;
            const char* r01 = winc + (wc0*WIN_W + wx1)*128;
            const char* r10 = winc + (wc1*WIN_W + wx0)*128;
            const char* r11 = winc + (wc1*WIN_W + wx1)*128;
            uint4 cb0 = *(const uint4*)(r00 + ((l4 ^ s0) << 4));
            uint4 cb1 = *(const uint4*)(r00 + (((l4+4) ^ s0) << 4));
            uint4 cb2 = *(const uint4*)(r01 + ((l4 ^ s1) << 4));
            uint4 cb3 = *(const uint4*)(r01 + (((l4+4) ^ s1) << 4));
            uint4 cb4 = *(const uint4*)(r10 + ((l4 ^ s0) << 4));
            uint4 cb5 = *(const uint4*)(r10 + (((l4+4) ^ s0) << 4));
            uint4 cb6 = *(const uint4*)(r11 + ((l4 ^ s1) << 4));
            uint4 cb7 = *(const uint4*)(r11 + (((l4+4) ^ s1) << 4));

            bool oob = (yv0 && (unsigned)wr0 > 5u) || (yv1 && (unsigned)wr1 > 5u)
                    || (xv0 && !inW0) || (xv1 && !inW1);
            if (__builtin_expect(oob, 0)) {
                int yc0 = y0 < 0 ? 0 : (y0 > 127 ? 127 : y0);
                int yc1 = y1 < 0 ? 0 : (y1 > 127 ? 127 : y1);
                int xc0 = x0i < 0 ? 0 : (x0i > 127 ? 127 : x0i);
                int xc1 = x1  < 0 ? 0 : (x1  > 127 ? 127 : x1);
                const unsigned short* p00 = xpb + (size_t)(yc0*128 + xc0)*64 + 8*l4;
                const unsigned short* p01 = xpb + (size_t)(yc0*128 + xc1)*64 + 8*l4;
                const unsigned short* p10 = xpb + (size_t)(yc1*128 + xc0)*64 + 8*l4;
                const unsigned short* p11 = xpb + (size_t)(yc1*128 + xc1)*64 + 8*l4;
                cb0 = *(const uint4*)(p00);  cb1 = *(const uint4*)(p00 + 32);
                cb2 = *(const uint4*)(p01);  cb3 = *(const uint4*)(p01 + 32);
                cb4 = *(const uint4*)(p10);  cb5 = *(const uint4*)(p10 + 32);
                cb6 = *(const uint4*)(p11);  cb7 = *(const uint4*)(p11 + 32);
            }

            float u00 = (1.f - wy) * (1.f - wx) * M * ((yv0 && xv0) ? 1.f : 0.f);
            float u01 = (1.f - wy) * wx         * M * ((yv0 && xv1) ? 1.f : 0.f);
            float u10 = wy * (1.f - wx)         * M * ((yv1 && xv0) ? 1.f : 0.f);
            float u11 = wy * wx                 * M * ((yv1 && xv1) ? 1.f : 0.f);

            unsigned pk0[4], pk1[4];
            #pragma unroll
            for (int d = 0; d < 4; ++d) {
                unsigned q00, q01, q10, q11;
                q00 = cb0[d]; q01 = cb2[d]; q10 = cb4[d]; q11 = cb6[d];
                {
                    float slo = bf_lo(q00)*u00 + bf_lo(q01)*u01 + bf_lo(q10)*u10 + bf_lo(q11)*u11;
                    float shi = bf_hi(q00)*u00 + bf_hi(q01)*u01 + bf_hi(q10)*u10 + bf_hi(q11)*u11;
                    pk0[d] = cvtpk(slo, shi);
                }
                q00 = cb1[d]; q01 = cb3[d]; q10 = cb5[d]; q11 = cb7[d];
                {
                    float slo = bf_lo(q00)*u00 + bf_lo(q01)*u01 + bf_lo(q10)*u10 + bf_lo(q11)*u11;
                    float shi = bf_hi(q00)*u00 + bf_hi(q01)*u01 + bf_hi(q10)*u10 + bf_hi(q11)*u11;
                    pk1[d] = cvtpk(slo, shi);
                }
            }
            A[j][0] = __builtin_bit_cast(bf16x8, make_uint4(pk0[0], pk0[1], pk0[2], pk0[3]));
            A[j][1] = __builtin_bit_cast(bf16x8, make_uint4(pk1[0], pk1[1], pk1[2], pk1[3]));
        }

        #pragma unroll
        for (int j = 0; j < 2; ++j)
            #pragma unroll
            for (int f = 0; f < 4; ++f) {
                acc[j][f] = __builtin_amdgcn_mfma_f32_16x16x32_bf16(A[j][0], Bs0[f], acc[j][f], 0,0,0);
                acc[j][f] = __builtin_amdgcn_mfma_f32_16x16x32_bf16(A[j][1], Bs1[f], acc[j][f], 0,0,0);
            }
        #pragma unroll
        for (int f = 0; f < 4; ++f) {
            Bs0[f] = *(const bf16x8*)(Wb2 + (size_t)(kk*16 +  4 + f) * 512 + lane * 8);
            Bs1[f] = *(const bf16x8*)(Wb2 + (size_t)(kk*16 + 12 + f) * 512 + lane * 8);
        }
        #pragma unroll
        for (int j = 0; j < 2; ++j)
            #pragma unroll
            for (int f = 0; f < 4; ++f) {
                acc[j][4+f] = __builtin_amdgcn_mfma_f32_16x16x32_bf16(A[j][0], Bs0[f], acc[j][4+f], 0,0,0);
                acc[j][4+f] = __builtin_amdgcn_mfma_f32_16x16x32_bf16(A[j][1], Bs1[f], acc[j][4+f], 0,0,0);
            }
    }

    // ---- epilogue: two cout-halves through the 33KB epi overlay ----
    __syncthreads();   // all waves done reading window
    #pragma unroll
    for (int half = 0; half < 2; ++half) {
        #pragma unroll
        for (int j = 0; j < 2; ++j)
            #pragma unroll
            for (int ff = 0; ff < 4; ++ff)
                *(f32x4*)(epi + (size_t)(16*ff + l15) * 130 + 32*wv + 16*j + 4*l4)
                    = acc[j][4*half + ff];
        __syncthreads();
        float* ob = out + (size_t)b * COUTC * HWC + (size_t)(64*half) * HWC
                  + h0 * 128 + x0w;
        #pragma unroll
        for (int it = 0; it < 8; ++it) {
            int idx = it * 256 + tid;         // 0..2047 f32x4
            int col = idx >> 5, q = idx & 31; // co_local, px-quad
            int p = 4 * q;                    // block px 0..124
            f32x4 v = *(const f32x4*)(epi + (size_t)col * 130 + p);
            *(f32x4*)(ob + (size_t)col * HWC + (p >> 6) * 128 + (p & 63)) = v;
        }
        __syncthreads();
    }
}

extern "C" void kernel_launch(void* const* d_in, const int* in_sizes, int n_in,
                              void* d_out, int out_size, void* d_ws, size_t ws_size,
                              hipStream_t stream)
{
    const float* x     = (const float*)d_in[0];
    const float* pre_w = (const float*)d_in[1];
    const float* pre_b = (const float*)d_in[2];
    const float* off_w = (const float*)d_in[3];
    const float* off_b = (const float*)d_in[4];
    const float* mod_w = (const float*)d_in[5];
    const float* mod_b = (const float*)d_in[6];
    const float* reg_w = (const float*)d_in[7];
    float* out = (float*)d_out;

    unsigned short* xp  = (unsigned short*)d_ws;                             // 16,777,216 B
    unsigned short* Wb2 = (unsigned short*)((char*)d_ws + 16777216);         //    147,456 B
    unsigned short* Wc3 = (unsigned short*)((char*)d_ws + 16924672);         //     36,864 B
    unsigned short* Wp2 = (unsigned short*)((char*)d_ws + 16961536);         //      8,192 B

    prep_weights<<<dim3(376), dim3(256), 0, stream>>>(off_w, mod_w, reg_w, pre_w, Wb2, Wc3, Wp2);
    conv1x1     <<<dim3(512), dim3(256), 0, stream>>>(x, Wp2, pre_b, xp);
    gather_einsum<<<dim3(1024), dim3(256), 0, stream>>>(xp, Wb2, Wc3, off_b, mod_b, out);
}

// Round 18
// 109.096 us; speedup vs baseline: 1.0667x; 1.0667x over previous
//
#include <hip/hip_runtime.h>
#include <hip/hip_bf16.h>
#include <cstdint>
#include <cstddef>

#define BATCH 8
#define CINC  64
#define HH    128
#define WWW   128
#define COUTC 128
#define KKC   9
#define KDIM  576
#define HWC   (HH*WWW)      // 16384
#define NPX   (BATCH*HWC)   // 131072

#define WIN_W 64
#define LDS_SZ (6*WIN_W*128)   // 49152 B -> 3 blocks/CU

typedef float f32x4 __attribute__((ext_vector_type(4)));
typedef short bf16x8 __attribute__((ext_vector_type(8)));

static __device__ __forceinline__ unsigned short f2bf(float f){
    unsigned u = __builtin_bit_cast(unsigned, f);
    u += 0x7fffu + ((u >> 16) & 1u);
    return (unsigned short)(u >> 16);
}
static __device__ __forceinline__ float bf_lo(unsigned u){
    return __builtin_bit_cast(float, u << 16);
}
static __device__ __forceinline__ float bf_hi(unsigned u){
    return __builtin_bit_cast(float, u & 0xffff0000u);
}
static __device__ __forceinline__ unsigned cvtpk(float lo, float hi){
    unsigned r;
    asm("v_cvt_pk_bf16_f32 %0, %1, %2" : "=v"(r) : "v"(lo), "v"(hi));
    return r;
}

// ---- K0: pack weights into per-wave-fragment coalesced layouts (r14) -------
__global__ __launch_bounds__(256) void prep_weights(
        const float* __restrict__ off_w, const float* __restrict__ mod_w,
        const float* __restrict__ reg_w, const float* __restrict__ pre_w,
        unsigned short* __restrict__ Wb2, unsigned short* __restrict__ Wc2,
        unsigned short* __restrict__ Wp2)
{
    int idx = blockIdx.x * 256 + threadIdx.x;      // 0..96255
    if (idx < 73728) {
        int chunk = idx >> 9, within = idx & 511;
        int lane = within >> 3, j = within & 7;
        int kk = chunk >> 4, s = (chunk >> 3) & 1, cog = chunk & 7;
        int o = cog * 16 + (lane & 15);
        int c = 32*s + 8*(lane >> 4) + j;
        Wb2[idx] = f2bf(reg_w[(o * CINC + c) * KKC + kk]);
    }
    int idx2 = idx - 73728;
    if (idx2 >= 0 && idx2 < 18432) {
        int chunk = idx2 >> 9, within = idx2 & 511;
        int lane = within >> 3, j = within & 7;
        int kk = chunk >> 2, s = (chunk >> 1) & 1, cog = chunk & 1;
        int o = cog * 16 + (lane & 15);
        int c = 32*s + 8*(lane >> 4) + j;
        float v = 0.f;
        if (o < 18)      v = off_w[(o * CINC + c) * KKC + kk];
        else if (o < 27) v = mod_w[((o - 18) * CINC + c) * KKC + kk];
        Wc2[idx2] = f2bf(v);
    }
    int idx3 = idx - 92160;
    if (idx3 >= 0 && idx3 < 4096) {
        int chunk = idx3 >> 9, within = idx3 & 511;
        int lane = within >> 3, j = within & 7;
        int s = chunk >> 2, fn = chunk & 3;
        int o = fn * 16 + (lane & 15);
        int c = 32*s + 8*(lane >> 4) + j;
        Wp2[idx3] = f2bf(pre_w[o * CINC + c]);
    }
}

// ---- K1: 1x1 conv via MFMA, NCHW f32 -> NHWC bf16 (r14, unchanged) ---------
__global__ __launch_bounds__(256) void conv1x1(
        const float* __restrict__ x, const unsigned short* __restrict__ Wp2,
        const float* __restrict__ pre_b, unsigned short* __restrict__ xp)
{
    __shared__ unsigned short slab[4][64 * 72];

    const int tid = threadIdx.x;
    const int lane = tid & 63;
    const int wv   = tid >> 6;
    const int l15  = lane & 15;
    const int l4   = lane >> 4;

    int bid = (int)blockIdx.x;
    int bswz = (bid & 7) * 64 + (bid >> 3);
    int pxb = bswz * 256 + wv * 64;
    int b = pxb >> 14, hw0 = pxb & 16383;
    const float* xb = x + (size_t)b * CINC * HWC + hw0;

    bf16x8 bw[4][2];
    #pragma unroll
    for (int fn = 0; fn < 4; ++fn)
        #pragma unroll
        for (int s = 0; s < 2; ++s)
            bw[fn][s] = *(const bf16x8*)(Wp2 + (size_t)(s*4 + fn) * 512 + lane * 8);
    float pb[4];
    #pragma unroll
    for (int fn = 0; fn < 4; ++fn) pb[fn] = pre_b[16*fn + l15];

    f32x4 acc[4][4];
    #pragma unroll
    for (int su = 0; su < 4; ++su)
        #pragma unroll
        for (int fn = 0; fn < 4; ++fn) acc[su][fn] = (f32x4){0.f,0.f,0.f,0.f};

    #pragma unroll
    for (int su = 0; su < 4; ++su) {
        #pragma unroll
        for (int s = 0; s < 2; ++s) {
            float f[8];
            #pragma unroll
            for (int j = 0; j < 8; ++j)
                f[j] = xb[(size_t)(s*32 + 8*l4 + j) * HWC + su*16 + l15];
            unsigned pk[4];
            #pragma unroll
            for (int d = 0; d < 4; ++d) pk[d] = cvtpk(f[2*d], f[2*d+1]);
            bf16x8 A = __builtin_bit_cast(bf16x8, make_uint4(pk[0], pk[1], pk[2], pk[3]));
            #pragma unroll
            for (int fn = 0; fn < 4; ++fn)
                acc[su][fn] = __builtin_amdgcn_mfma_f32_16x16x32_bf16(A, bw[fn][s], acc[su][fn], 0,0,0);
        }
    }

    unsigned short* sl = slab[wv];
    #pragma unroll
    for (int su = 0; su < 4; ++su)
        #pragma unroll
        for (int fn = 0; fn < 4; ++fn)
            #pragma unroll
            for (int r = 0; r < 4; ++r)
                sl[(su*16 + 4*l4 + r) * 72 + 16*fn + l15] = f2bf(acc[su][fn][r] + pb[fn]);
    const uint4* srow = (const uint4*)(sl + lane * 72);
    uint4* drow = (uint4*)(xp + (size_t)(pxb + lane) * 64);
    #pragma unroll
    for (int q = 0; q < 8; ++q) drow[q] = srow[q];
}

// ---- K3: fused; window-only LDS (49K) => 3 blocks/CU; coords via gco -------
// 1024 blocks x 256 thr (4 waves). Block = 2 rows x 64 px. Wave = 32 px x
// 128 couts (r14 shape). Phase O (non-swapped) from window (+per-lane global
// edge fallback), coords written to gco (global scratch, L2-hot) and read
// back per-kk in the main loop. Main loop = r14's register-direct lerp->MFMA.
__global__ __launch_bounds__(256, 3) void gather_einsum(
        const unsigned short* __restrict__ xp,
        const unsigned short* __restrict__ Wb2,
        const unsigned short* __restrict__ Wc2,
        const float* __restrict__ off_b,
        const float* __restrict__ mod_b,
        float* __restrict__ gco,
        float* __restrict__ out)
{
    __shared__ char smem[LDS_SZ];
    char* winc = smem;                       // [6][64] px, 128B, swizzled
    float* epi = (float*)smem;               // overlay: [64 co][130] f32

    const int tid  = (int)threadIdx.x;
    const int lane = tid & 63;
    const int wv   = tid >> 6;       // 0..3
    const int l15  = lane & 15;
    const int l4   = lane >> 4;

    int bid = (int)blockIdx.x;
    int bswz = (bid & 7) * 128 + (bid >> 3);  // image = bid&7 (1024%8==0)
    const int b   = bswz >> 7;
    const int rem = bswz & 127;
    const int h0  = (rem >> 1) << 1;          // row pair
    const int x0w = (rem & 1) << 6;           // x half

    const unsigned short* xpb = xp + (size_t)b * HWC * CINC;
    float* gcb = gco + (size_t)bid * 3456;    // [27][128 px] f32

    // ---- stage window rows h0-2..h0+3, x = x0w..x0w+63, swizzled ----
    #pragma unroll
    for (int i = 0; i < 12; ++i) {
        int c = i * 256 + tid;            // 0..3071 16B-chunks
        int r = c >> 9;
        int cr = c & 511;
        int wx = cr >> 3, g = cr & 7;
        int y = h0 - 2 + r;
        uint4 v = make_uint4(0u,0u,0u,0u);
        if ((unsigned)y < 128u)
            v = *(const uint4*)(xpb + ((size_t)y * 128 + x0w + wx) * 64 + g * 8);
        *(uint4*)(winc + (r*WIN_W + wx)*128 + ((g ^ (wx & 7)) << 4)) = v;
    }
    __syncthreads();

    // ---- Phase O: offset/mask conv (non-swapped); wave = 32 px ----
    const int hrow = wv >> 1;
    const int xsl  = (wv & 1) * 32;
    {
        f32x4 aco[2][2];
        #pragma unroll
        for (int j = 0; j < 2; ++j)
            #pragma unroll
            for (int fn = 0; fn < 2; ++fn) aco[j][fn] = (f32x4){0.f,0.f,0.f,0.f};

        #pragma unroll
        for (int kk = 0; kk < 9; ++kk) {
            bf16x8 bc0[2], bc1[2];
            #pragma unroll
            for (int fn = 0; fn < 2; ++fn) {
                bc0[fn] = *(const bf16x8*)(Wc2 + (size_t)(kk*4     + fn) * 512 + lane * 8);
                bc1[fn] = *(const bf16x8*)(Wc2 + (size_t)(kk*4 + 2 + fn) * 512 + lane * 8);
            }
            int wr_ = hrow + (kk / 3) + 1;
            int y_  = h0 + hrow + kk/3 - 1;
            bool yv = (unsigned)y_ < 128u;
            int dx = kk % 3 - 1;
            #pragma unroll
            for (int j = 0; j < 2; ++j) {
                int gx  = x0w + xsl + 16*j + l15;   // global x of px
                int gxx = gx + dx;
                int wx2 = gxx - x0w;
                bool in_win = (unsigned)wx2 < (unsigned)WIN_W;
                int wxc = wx2 < 0 ? 0 : (wx2 > WIN_W-1 ? WIN_W-1 : wx2);
                int sx = wxc & 7;
                const char* rr = winc + (wr_*WIN_W + wxc)*128;
                uint4 a0 = *(const uint4*)(rr + ((l4 ^ sx) << 4));
                uint4 a1 = *(const uint4*)(rr + (((l4+4) ^ sx) << 4));
                if (__builtin_expect(!in_win, 0)) {
                    bool vld = yv && ((unsigned)gxx < 128u);
                    const unsigned short* gp = xpb
                        + (size_t)(((y_ & 127) * 128) + (gxx & 127)) * 64 + 8*l4;
                    uint4 z = make_uint4(0u,0u,0u,0u);
                    a0 = vld ? *(const uint4*)(gp)      : z;
                    a1 = vld ? *(const uint4*)(gp + 32) : z;
                }
                bf16x8 A0 = __builtin_bit_cast(bf16x8, a0);
                bf16x8 A1 = __builtin_bit_cast(bf16x8, a1);
                #pragma unroll
                for (int fn = 0; fn < 2; ++fn) {
                    aco[j][fn] = __builtin_amdgcn_mfma_f32_16x16x32_bf16(A0, bc0[fn], aco[j][fn], 0,0,0);
                    aco[j][fn] = __builtin_amdgcn_mfma_f32_16x16x32_bf16(A1, bc1[fn], aco[j][fn], 0,0,0);
                }
            }
        }
        // epilogue-O: D -> gco[o][px] (L2-resident scratch)
        #pragma unroll
        for (int j = 0; j < 2; ++j)
        #pragma unroll
        for (int fn = 0; fn < 2; ++fn) {
            int o = 16*fn + l15;
            #pragma unroll
            for (int r = 0; r < 4; ++r) {
                int pr = 4*l4 + r;
                int p  = hrow*64 + xsl + 16*j + pr;    // block px 0..127
                float v = aco[j][fn][r];
                if (o < 18) {
                    v += off_b[o];
                    int k = o >> 1;
                    if ((o & 1) == 0) v += (float)(h0 + hrow - 1 + k/3);
                    else              v += (float)(x0w + xsl + 16*j + pr - 1 + (k % 3));
                } else if (o < 27) {
                    v = 2.f / (1.f + __expf(-(v + mod_b[o - 18])));
                }
                if (o < 27) gcb[o*128 + p] = v;
            }
        }
    }
    __syncthreads();   // drain vmcnt: gco visible to all waves via L2

    // ---- main loop: coords from gco; register-direct lerp -> MFMA ----
    f32x4 acc[2][8];
    #pragma unroll
    for (int j = 0; j < 2; ++j)
        #pragma unroll
        for (int fn = 0; fn < 8; ++fn) acc[j][fn] = (f32x4){0.f,0.f,0.f,0.f};

    #pragma unroll 1
    for (int kk = 0; kk < 9; ++kk) {
        bf16x8 Bs0[4], Bs1[4];
        #pragma unroll
        for (int f = 0; f < 4; ++f) {
            Bs0[f] = *(const bf16x8*)(Wb2 + (size_t)(kk*16 +      f) * 512 + lane * 8);
            Bs1[f] = *(const bf16x8*)(Wb2 + (size_t)(kk*16 +  8 + f) * 512 + lane * 8);
        }

        bf16x8 A[2][2];
        #pragma unroll
        for (int j = 0; j < 2; ++j) {
            int p = wv*32 + 16*j + l15;
            float Y = gcb[(2*kk    )*128 + p];
            float X = gcb[(2*kk + 1)*128 + p];
            float M = gcb[(18 + kk )*128 + p];
            float yf = floorf(Y), xf = floorf(X);
            float wy = Y - yf, wx = X - xf;
            int y0 = (int)yf, x0i = (int)xf;
            int y1 = y0 + 1, x1 = x0i + 1;
            bool yv0 = (unsigned)y0 < 128u, yv1 = (unsigned)y1 < 128u;
            bool xv0 = (unsigned)x0i < 128u, xv1 = (unsigned)x1 < 128u;
            int wr0 = y0 - (h0 - 2), wr1 = wr0 + 1;
            int wxi = x0i - x0w;
            bool inW0 = (unsigned)wxi < (unsigned)WIN_W;
            bool inW1 = (unsigned)(wxi + 1) < (unsigned)WIN_W;
            int wc0 = wr0 < 0 ? 0 : (wr0 > 5 ? 5 : wr0);
            int wc1 = wr1 < 0 ? 0 : (wr1 > 5 ? 5 : wr1);
            int wx0 = wxi < 0 ? 0 : (wxi > WIN_W-1 ? WIN_W-1 : wxi);
            int wx1 = wxi+1 < 0 ? 0 : (wxi+1 > WIN_W-1 ? WIN_W-1 : wxi+1);
            int s0 = wx0 & 7, s1 = wx1 & 7;

            const char* r00 = winc + (wc0*WIN_W + wx0)*128;
            const char* r01 = winc + (wc0*WIN_W + wx1)*128;
            const char* r10 = winc + (wc1*WIN_W + wx0)*128;
            const char* r11 = winc + (wc1*WIN_W + wx1)*128;
            uint4 cb0 = *(const uint4*)(r00 + ((l4 ^ s0) << 4));
            uint4 cb1 = *(const uint4*)(r00 + (((l4+4) ^ s0) << 4));
            uint4 cb2 = *(const uint4*)(r01 + ((l4 ^ s1) << 4));
            uint4 cb3 = *(const uint4*)(r01 + (((l4+4) ^ s1) << 4));
            uint4 cb4 = *(const uint4*)(r10 + ((l4 ^ s0) << 4));
            uint4 cb5 = *(const uint4*)(r10 + (((l4+4) ^ s0) << 4));
            uint4 cb6 = *(const uint4*)(r11 + ((l4 ^ s1) << 4));
            uint4 cb7 = *(const uint4*)(r11 + (((l4+4) ^ s1) << 4));

            bool oob = (yv0 && (unsigned)wr0 > 5u) || (yv1 && (unsigned)wr1 > 5u)
                    || (xv0 && !inW0) || (xv1 && !inW1);
            if (__builtin_expect(oob, 0)) {
                int yc0 = y0 < 0 ? 0 : (y0 > 127 ? 127 : y0);
                int yc1 = y1 < 0 ? 0 : (y1 > 127 ? 127 : y1);
                int xc0 = x0i < 0 ? 0 : (x0i > 127 ? 127 : x0i);
                int xc1 = x1  < 0 ? 0 : (x1  > 127 ? 127 : x1);
                const unsigned short* p00 = xpb + (size_t)(yc0*128 + xc0)*64 + 8*l4;
                const unsigned short* p01 = xpb + (size_t)(yc0*128 + xc1)*64 + 8*l4;
                const unsigned short* p10 = xpb + (size_t)(yc1*128 + xc0)*64 + 8*l4;
                const unsigned short* p11 = xpb + (size_t)(yc1*128 + xc1)*64 + 8*l4;
                cb0 = *(const uint4*)(p00);  cb1 = *(const uint4*)(p00 + 32);
                cb2 = *(const uint4*)(p01);  cb3 = *(const uint4*)(p01 + 32);
                cb4 = *(const uint4*)(p10);  cb5 = *(const uint4*)(p10 + 32);
                cb6 = *(const uint4*)(p11);  cb7 = *(const uint4*)(p11 + 32);
            }

            float u00 = (1.f - wy) * (1.f - wx) * M * ((yv0 && xv0) ? 1.f : 0.f);
            float u01 = (1.f - wy) * wx         * M * ((yv0 && xv1) ? 1.f : 0.f);
            float u10 = wy * (1.f - wx)         * M * ((yv1 && xv0) ? 1.f : 0.f);
            float u11 = wy * wx                 * M * ((yv1 && xv1) ? 1.f : 0.f);

            unsigned pk0[4], pk1[4];
            #pragma unroll
            for (int d = 0; d < 4; ++d) {
                unsigned q00, q01, q10, q11;
                q00 = cb0[d]; q01 = cb2[d]; q10 = cb4[d]; q11 = cb6[d];
                {
                    float slo = bf_lo(q00)*u00 + bf_lo(q01)*u01 + bf_lo(q10)*u10 + bf_lo(q11)*u11;
                    float shi = bf_hi(q00)*u00 + bf_hi(q01)*u01 + bf_hi(q10)*u10 + bf_hi(q11)*u11;
                    pk0[d] = cvtpk(slo, shi);
                }
                q00 = cb1[d]; q01 = cb3[d]; q10 = cb5[d]; q11 = cb7[d];
                {
                    float slo = bf_lo(q00)*u00 + bf_lo(q01)*u01 + bf_lo(q10)*u10 + bf_lo(q11)*u11;
                    float shi = bf_hi(q00)*u00 + bf_hi(q01)*u01 + bf_hi(q10)*u10 + bf_hi(q11)*u11;
                    pk1[d] = cvtpk(slo, shi);
                }
            }
            A[j][0] = __builtin_bit_cast(bf16x8, make_uint4(pk0[0], pk0[1], pk0[2], pk0[3]));
            A[j][1] = __builtin_bit_cast(bf16x8, make_uint4(pk1[0], pk1[1], pk1[2], pk1[3]));
        }

        #pragma unroll
        for (int j = 0; j < 2; ++j)
            #pragma unroll
            for (int f = 0; f < 4; ++f) {
                acc[j][f] = __builtin_amdgcn_mfma_f32_16x16x32_bf16(A[j][0], Bs0[f], acc[j][f], 0,0,0);
                acc[j][f] = __builtin_amdgcn_mfma_f32_16x16x32_bf16(A[j][1], Bs1[f], acc[j][f], 0,0,0);
            }
        #pragma unroll
        for (int f = 0; f < 4; ++f) {
            Bs0[f] = *(const bf16x8*)(Wb2 + (size_t)(kk*16 +  4 + f) * 512 + lane * 8);
            Bs1[f] = *(const bf16x8*)(Wb2 + (size_t)(kk*16 + 12 + f) * 512 + lane * 8);
        }
        #pragma unroll
        for (int j = 0; j < 2; ++j)
            #pragma unroll
            for (int f = 0; f < 4; ++f) {
                acc[j][4+f] = __builtin_amdgcn_mfma_f32_16x16x32_bf16(A[j][0], Bs0[f], acc[j][4+f], 0,0,0);
                acc[j][4+f] = __builtin_amdgcn_mfma_f32_16x16x32_bf16(A[j][1], Bs1[f], acc[j][4+f], 0,0,0);
            }
    }

    // ---- epilogue: two cout-halves through the epi overlay ----
    __syncthreads();   // all waves done reading window
    #pragma unroll
    for (int half = 0; half < 2; ++half) {
        #pragma unroll
        for (int j = 0; j < 2; ++j)
            #pragma unroll
            for (int ff = 0; ff < 4; ++ff)
                *(f32x4*)(epi + (size_t)(16*ff + l15) * 130 + 32*wv + 16*j + 4*l4)
                    = acc[j][4*half + ff];
        __syncthreads();
        float* ob = out + (size_t)b * COUTC * HWC + (size_t)(64*half) * HWC
                  + h0 * 128 + x0w;
        #pragma unroll
        for (int it = 0; it < 8; ++it) {
            int idx = it * 256 + tid;         // 0..2047 f32x4
            int col = idx >> 5, q = idx & 31; // co_local, px-quad
            int p = 4 * q;                    // block px 0..124
            f32x4 v = *(const f32x4*)(epi + (size_t)col * 130 + p);
            *(f32x4*)(ob + (size_t)col * HWC + (p >> 6) * 128 + (p & 63)) = v;
        }
        __syncthreads();
    }
}

extern "C" void kernel_launch(void* const* d_in, const int* in_sizes, int n_in,
                              void* d_out, int out_size, void* d_ws, size_t ws_size,
                              hipStream_t stream)
{
    const float* x     = (const float*)d_in[0];
    const float* pre_w = (const float*)d_in[1];
    const float* pre_b = (const float*)d_in[2];
    const float* off_w = (const float*)d_in[3];
    const float* off_b = (const float*)d_in[4];
    const float* mod_w = (const float*)d_in[5];
    const float* mod_b = (const float*)d_in[6];
    const float* reg_w = (const float*)d_in[7];
    float* out = (float*)d_out;

    unsigned short* xp  = (unsigned short*)d_ws;                             // 16,777,216 B
    unsigned short* Wb2 = (unsigned short*)((char*)d_ws + 16777216);         //    147,456 B
    unsigned short* Wc2 = (unsigned short*)((char*)d_ws + 16924672);         //     36,864 B
    unsigned short* Wp2 = (unsigned short*)((char*)d_ws + 16961536);         //      8,192 B
    float* gco = (float*)((char*)d_ws + 16969728);                           // 14,155,776 B

    prep_weights<<<dim3(376), dim3(256), 0, stream>>>(off_w, mod_w, reg_w, pre_w, Wb2, Wc2, Wp2);
    conv1x1     <<<dim3(512), dim3(256), 0, stream>>>(x, Wp2, pre_b, xp);
    gather_einsum<<<dim3(1024), dim3(256), 0, stream>>>(xp, Wb2, Wc2, off_b, mod_b, gco, out);
}

// Round 19
// 83.917 us; speedup vs baseline: 1.3868x; 1.3001x over previous
//
#include <hip/hip_runtime.h>
#include <hip/hip_bf16.h>
#include <cstdint>
#include <cstddef>

#define BATCH 8
#define CINC  64
#define HH    128
#define WWW   128
#define COUTC 128
#define KKC   9
#define KDIM  576
#define HWC   (HH*WWW)      // 16384
#define NPX   (BATCH*HWC)   // 131072

#define DT_BASE 98304       // window = 6*128*128 B; Dt after it

typedef float f32x4 __attribute__((ext_vector_type(4)));
typedef short bf16x8 __attribute__((ext_vector_type(8)));

static __device__ __forceinline__ unsigned short f2bf(float f){
    unsigned u = __builtin_bit_cast(unsigned, f);
    u += 0x7fffu + ((u >> 16) & 1u);
    return (unsigned short)(u >> 16);
}
static __device__ __forceinline__ float bf_lo(unsigned u){
    return __builtin_bit_cast(float, u << 16);
}
static __device__ __forceinline__ float bf_hi(unsigned u){
    return __builtin_bit_cast(float, u & 0xffff0000u);
}
static __device__ __forceinline__ unsigned cvtpk(float lo, float hi){
    unsigned r;
    asm("v_cvt_pk_bf16_f32 %0, %1, %2" : "=v"(r) : "v"(lo), "v"(hi));
    return r;
}

// ---- K01: merged {conv1x1 (blocks 0..511)} + {Wb2/Wc2 packing (512..871)} --
// conv1x1 self-converts pre_w (no Wp2 dependency); packing blocks produce the
// per-wave-fragment coalesced layouts consumed by the NEXT kernel.
__global__ __launch_bounds__(256) void prep_conv(
        const float* __restrict__ x, const float* __restrict__ pre_w,
        const float* __restrict__ pre_b,
        const float* __restrict__ off_w, const float* __restrict__ mod_w,
        const float* __restrict__ reg_w,
        unsigned short* __restrict__ xp,
        unsigned short* __restrict__ Wb2, unsigned short* __restrict__ Wc2)
{
    const int tid = threadIdx.x;
    int bid = (int)blockIdx.x;

    if (bid >= 512) {
        // ---- weight packing: 360 blocks cover 92160 elements ----
        int idx = (bid - 512) * 256 + tid;     // 0..92159
        if (idx < 73728) {
            int chunk = idx >> 9, within = idx & 511;
            int lane = within >> 3, j = within & 7;
            int kk = chunk >> 4, s = (chunk >> 3) & 1, cog = chunk & 7;
            int o = cog * 16 + (lane & 15);
            int c = 32*s + 8*(lane >> 4) + j;
            Wb2[idx] = f2bf(reg_w[(o * CINC + c) * KKC + kk]);
        } else {
            int idx2 = idx - 73728;            // 0..18431
            int chunk = idx2 >> 9, within = idx2 & 511;
            int lane = within >> 3, j = within & 7;
            int kk = chunk >> 2, s = (chunk >> 1) & 1, cog = chunk & 1;
            int o = cog * 16 + (lane & 15);
            int c = 32*s + 8*(lane >> 4) + j;
            float v = 0.f;
            if (o < 18)      v = off_w[(o * CINC + c) * KKC + kk];
            else if (o < 27) v = mod_w[((o - 18) * CINC + c) * KKC + kk];
            Wc2[idx2] = f2bf(v);
        }
        return;
    }

    // ---- conv1x1: NCHW f32 -> NHWC bf16 via MFMA ----
    __shared__ unsigned short slab[4][64 * 72];

    const int lane = tid & 63;
    const int wv   = tid >> 6;
    const int l15  = lane & 15;
    const int l4   = lane >> 4;

    int bswz = (bid & 7) * 64 + (bid >> 3);
    int pxb = bswz * 256 + wv * 64;
    int b = pxb >> 14, hw0 = pxb & 16383;
    const float* xb = x + (size_t)b * CINC * HWC + hw0;

    // self-convert pre_w into B-fragments: o = 16*fn + l15, c = 32*s + 8*l4 + j
    bf16x8 bw[4][2];
    #pragma unroll
    for (int fn = 0; fn < 4; ++fn)
        #pragma unroll
        for (int s = 0; s < 2; ++s) {
            const float* wp = pre_w + (size_t)(16*fn + l15) * 64 + 32*s + 8*l4;
            f32x4 w0 = *(const f32x4*)(wp);
            f32x4 w1 = *(const f32x4*)(wp + 4);
            bw[fn][s] = __builtin_bit_cast(bf16x8, make_uint4(
                cvtpk(w0.x, w0.y), cvtpk(w0.z, w0.w),
                cvtpk(w1.x, w1.y), cvtpk(w1.z, w1.w)));
        }
    float pb[4];
    #pragma unroll
    for (int fn = 0; fn < 4; ++fn) pb[fn] = pre_b[16*fn + l15];

    f32x4 acc[4][4];
    #pragma unroll
    for (int su = 0; su < 4; ++su)
        #pragma unroll
        for (int fn = 0; fn < 4; ++fn) acc[su][fn] = (f32x4){0.f,0.f,0.f,0.f};

    #pragma unroll
    for (int su = 0; su < 4; ++su) {
        #pragma unroll
        for (int s = 0; s < 2; ++s) {
            float f[8];
            #pragma unroll
            for (int j = 0; j < 8; ++j)
                f[j] = xb[(size_t)(s*32 + 8*l4 + j) * HWC + su*16 + l15];
            unsigned pk[4];
            #pragma unroll
            for (int d = 0; d < 4; ++d) pk[d] = cvtpk(f[2*d], f[2*d+1]);
            bf16x8 A = __builtin_bit_cast(bf16x8, make_uint4(pk[0], pk[1], pk[2], pk[3]));
            #pragma unroll
            for (int fn = 0; fn < 4; ++fn)
                acc[su][fn] = __builtin_amdgcn_mfma_f32_16x16x32_bf16(A, bw[fn][s], acc[su][fn], 0,0,0);
        }
    }

    unsigned short* sl = slab[wv];
    #pragma unroll
    for (int su = 0; su < 4; ++su)
        #pragma unroll
        for (int fn = 0; fn < 4; ++fn)
            #pragma unroll
            for (int r = 0; r < 4; ++r)
                sl[(su*16 + 4*l4 + r) * 72 + 16*fn + l15] = f2bf(acc[su][fn][r] + pb[fn]);
    const uint4* srow = (const uint4*)(sl + lane * 72);
    uint4* drow = (uint4*)(xp + (size_t)(pxb + lane) * 64);
    #pragma unroll
    for (int q = 0; q < 8; ++q) drow[q] = srow[q];
}

// ---- K3: fused, register-direct lerp->MFMA, barrier-free main loop (r14) ---
// 512 blocks x 512 thr (8 waves, 2/SIMD). Block = 2 rows x 128 px.
// LDS: window 6x128px x128B (swizzled, 98KB) + Dt coords (30KB); epi overlays.
// Wave owns 32 px x ALL 128 couts: lerp -> A-frags in REGISTERS -> MFMA
// directly. B-frags = coalesced 1KB loads from Wb2 (L2-hot). Main loop has
// NO barriers (window read-only, Dt same-wave).
__global__ __launch_bounds__(512, 2) void gather_einsum(
        const unsigned short* __restrict__ xp,
        const unsigned short* __restrict__ Wb2,
        const unsigned short* __restrict__ Wc2,
        const float* __restrict__ off_b,
        const float* __restrict__ mod_b,
        float* __restrict__ out)
{
    __shared__ char smem[133120];
    char* winc = smem;                       // [6][128] px, 128B, swizzled
    float* epi = (float*)smem;               // epilogue [128 co][260] f32
    float* Dt  = (float*)(smem + DT_BASE);   // [256 px][29] f32 coords

    const int tid  = (int)threadIdx.x;
    const int lane = tid & 63;
    const int wv   = tid >> 6;       // 0..7
    const int l15  = lane & 15;
    const int l4   = lane >> 4;

    int bid = (int)blockIdx.x;
    int bswz = (bid & 7) * 64 + (bid >> 3);   // image = bid&7 (512%8==0)
    const int b  = bswz >> 6;
    const int h0 = (bswz & 63) * 2;

    const unsigned short* xpb = xp + (size_t)b * HWC * CINC;

    // ---- stage window rows h0-2..h0+3, swizzled ----
    #pragma unroll
    for (int i = 0; i < 12; ++i) {
        int c = i * 512 + tid;            // 0..6143
        int r = c >> 10;
        int c10 = c & 1023;
        int xph = c10 >> 3, g = c10 & 7;
        int y = h0 - 2 + r;
        uint4 v = make_uint4(0u,0u,0u,0u);
        if ((unsigned)y < 128u)
            v = *(const uint4*)(xpb + ((size_t)y * 128 + xph) * 64 + g * 8);
        *(uint4*)(winc + (r*128 + xph)*128 + ((g ^ (xph & 7)) << 4)) = v;
    }
    __syncthreads();

    // ---- Phase O: offset/mask conv from window (8 waves, 32 px each) ----
    const int hrow = wv >> 2;
    const int x0w  = (wv & 3) * 32;
    {
        f32x4 aco[2][2];
        #pragma unroll
        for (int j = 0; j < 2; ++j)
            #pragma unroll
            for (int fn = 0; fn < 2; ++fn) aco[j][fn] = (f32x4){0.f,0.f,0.f,0.f};

        #pragma unroll
        for (int kk = 0; kk < 9; ++kk) {
            bf16x8 bc0[2], bc1[2];
            #pragma unroll
            for (int fn = 0; fn < 2; ++fn) {
                bc0[fn] = *(const bf16x8*)(Wc2 + (size_t)(kk*4     + fn) * 512 + lane * 8);
                bc1[fn] = *(const bf16x8*)(Wc2 + (size_t)(kk*4 + 2 + fn) * 512 + lane * 8);
            }
            int wr_ = hrow + (kk / 3) + 1;
            #pragma unroll
            for (int j = 0; j < 2; ++j) {
                int xx = x0w + j*16 + l15 + (kk % 3) - 1;
                bool xv = (unsigned)xx < 128u;
                int xc = xx < 0 ? 0 : (xx > 127 ? 127 : xx);
                int sx = xc & 7;
                const char* rr = winc + (wr_*128 + xc)*128;
                uint4 a0 = *(const uint4*)(rr + ((l4 ^ sx) << 4));
                uint4 a1 = *(const uint4*)(rr + (((l4+4) ^ sx) << 4));
                if (!xv) { a0 = make_uint4(0,0,0,0); a1 = make_uint4(0,0,0,0); }
                bf16x8 A0 = __builtin_bit_cast(bf16x8, a0);
                bf16x8 A1 = __builtin_bit_cast(bf16x8, a1);
                #pragma unroll
                for (int fn = 0; fn < 2; ++fn) {
                    aco[j][fn] = __builtin_amdgcn_mfma_f32_16x16x32_bf16(A0, bc0[fn], aco[j][fn], 0,0,0);
                    aco[j][fn] = __builtin_amdgcn_mfma_f32_16x16x32_bf16(A1, bc1[fn], aco[j][fn], 0,0,0);
                }
            }
        }
        // D -> Dt[p][o] (pitch 29), same-wave producer/consumer
        #pragma unroll
        for (int j = 0; j < 2; ++j)
        #pragma unroll
        for (int fn = 0; fn < 2; ++fn) {
            int o = 16*fn + l15;
            #pragma unroll
            for (int r = 0; r < 4; ++r) {
                int pr = 4*l4 + r;
                int p  = wv*32 + j*16 + pr;
                float v = aco[j][fn][r];
                if (o < 18) {
                    v += off_b[o];
                    int k = o >> 1;
                    if ((o & 1) == 0) v += (float)(h0 + hrow - 1 + k/3);
                    else              v += (float)(x0w + j*16 + pr - 1 + (k % 3));
                } else if (o < 27) {
                    v = 2.f / (1.f + __expf(-(v + mod_b[o - 18])));
                }
                if (o < 27) Dt[p*29 + o] = v;
            }
        }
    }
    // no barrier: Dt entries are produced and consumed by the SAME wave

    // ---- main loop: per kk {coords from Dt; lerp -> A regs; 32 MFMA} -------
    f32x4 acc[2][8];
    #pragma unroll
    for (int j = 0; j < 2; ++j)
        #pragma unroll
        for (int fn = 0; fn < 8; ++fn) acc[j][fn] = (f32x4){0.f,0.f,0.f,0.f};

    #pragma unroll 1
    for (int kk = 0; kk < 9; ++kk) {
        // B half 0 (cog 0..3), both K-chunks — coalesced 1KB loads, L2-hot
        bf16x8 Bs0[4], Bs1[4];
        #pragma unroll
        for (int f = 0; f < 4; ++f) {
            Bs0[f] = *(const bf16x8*)(Wb2 + (size_t)(kk*16 +      f) * 512 + lane * 8);
            Bs1[f] = *(const bf16x8*)(Wb2 + (size_t)(kk*16 +  8 + f) * 512 + lane * 8);
        }

        bf16x8 A[2][2];
        #pragma unroll
        for (int j = 0; j < 2; ++j) {
            int p = wv*32 + j*16 + l15;
            float Y = Dt[p*29 + 2*kk];
            float X = Dt[p*29 + 2*kk + 1];
            float M = Dt[p*29 + 18 + kk];
            float yf = floorf(Y), xf = floorf(X);
            float wy = Y - yf, wx = X - xf;
            int y0 = (int)yf, x0i = (int)xf;
            int y1 = y0 + 1, x1 = x0i + 1;
            bool yv0 = (unsigned)y0 < 128u, yv1 = (unsigned)y1 < 128u;
            bool xv0 = (unsigned)x0i < 128u, xv1 = (unsigned)x1 < 128u;
            int xc0 = x0i < 0 ? 0 : (x0i > 127 ? 127 : x0i);
            int xc1 = x1  < 0 ? 0 : (x1  > 127 ? 127 : x1);
            int wr0 = y0 - (h0 - 2), wr1 = wr0 + 1;
            int wc0 = wr0 < 0 ? 0 : (wr0 > 5 ? 5 : wr0);
            int wc1 = wr1 < 0 ? 0 : (wr1 > 5 ? 5 : wr1);
            int s0 = xc0 & 7, s1 = xc1 & 7;

            const char* r00 = winc + (wc0*128 + xc0)*128;
            const char* r01 = winc + (wc0*128 + xc1)*128;
            const char* r10 = winc + (wc1*128 + xc0)*128;
            const char* r11 = winc + (wc1*128 + xc1)*128;
            uint4 cb0 = *(const uint4*)(r00 + ((l4 ^ s0) << 4));
            uint4 cb1 = *(const uint4*)(r00 + (((l4+4) ^ s0) << 4));
            uint4 cb2 = *(const uint4*)(r01 + ((l4 ^ s1) << 4));
            uint4 cb3 = *(const uint4*)(r01 + (((l4+4) ^ s1) << 4));
            uint4 cb4 = *(const uint4*)(r10 + ((l4 ^ s0) << 4));
            uint4 cb5 = *(const uint4*)(r10 + (((l4+4) ^ s0) << 4));
            uint4 cb6 = *(const uint4*)(r11 + ((l4 ^ s1) << 4));
            uint4 cb7 = *(const uint4*)(r11 + (((l4+4) ^ s1) << 4));

            bool oob = (yv0 && (unsigned)wr0 > 5u) || (yv1 && (unsigned)wr1 > 5u);
            if (__builtin_expect(oob, 0)) {
                int yc0 = y0 < 0 ? 0 : (y0 > 127 ? 127 : y0);
                int yc1 = y1 < 0 ? 0 : (y1 > 127 ? 127 : y1);
                const unsigned short* p00 = xpb + (size_t)(yc0*128 + xc0)*64 + 8*l4;
                const unsigned short* p01 = xpb + (size_t)(yc0*128 + xc1)*64 + 8*l4;
                const unsigned short* p10 = xpb + (size_t)(yc1*128 + xc0)*64 + 8*l4;
                const unsigned short* p11 = xpb + (size_t)(yc1*128 + xc1)*64 + 8*l4;
                cb0 = *(const uint4*)(p00);  cb1 = *(const uint4*)(p00 + 32);
                cb2 = *(const uint4*)(p01);  cb3 = *(const uint4*)(p01 + 32);
                cb4 = *(const uint4*)(p10);  cb5 = *(const uint4*)(p10 + 32);
                cb6 = *(const uint4*)(p11);  cb7 = *(const uint4*)(p11 + 32);
            }

            float u00 = (1.f - wy) * (1.f - wx) * M * ((yv0 && xv0) ? 1.f : 0.f);
            float u01 = (1.f - wy) * wx         * M * ((yv0 && xv1) ? 1.f : 0.f);
            float u10 = wy * (1.f - wx)         * M * ((yv1 && xv0) ? 1.f : 0.f);
            float u11 = wy * wx                 * M * ((yv1 && xv1) ? 1.f : 0.f);

            unsigned pk0[4], pk1[4];
            #pragma unroll
            for (int d = 0; d < 4; ++d) {
                unsigned q00, q01, q10, q11;
                q00 = cb0[d]; q01 = cb2[d]; q10 = cb4[d]; q11 = cb6[d];
                {
                    float slo = bf_lo(q00)*u00 + bf_lo(q01)*u01 + bf_lo(q10)*u10 + bf_lo(q11)*u11;
                    float shi = bf_hi(q00)*u00 + bf_hi(q01)*u01 + bf_hi(q10)*u10 + bf_hi(q11)*u11;
                    pk0[d] = cvtpk(slo, shi);
                }
                q00 = cb1[d]; q01 = cb3[d]; q10 = cb5[d]; q11 = cb7[d];
                {
                    float slo = bf_lo(q00)*u00 + bf_lo(q01)*u01 + bf_lo(q10)*u10 + bf_lo(q11)*u11;
                    float shi = bf_hi(q00)*u00 + bf_hi(q01)*u01 + bf_hi(q10)*u10 + bf_hi(q11)*u11;
                    pk1[d] = cvtpk(slo, shi);
                }
            }
            A[j][0] = __builtin_bit_cast(bf16x8, make_uint4(pk0[0], pk0[1], pk0[2], pk0[3]));
            A[j][1] = __builtin_bit_cast(bf16x8, make_uint4(pk1[0], pk1[1], pk1[2], pk1[3]));
        }

        // MFMA half 0 (couts 0..63)
        #pragma unroll
        for (int j = 0; j < 2; ++j)
            #pragma unroll
            for (int f = 0; f < 4; ++f) {
                acc[j][f] = __builtin_amdgcn_mfma_f32_16x16x32_bf16(A[j][0], Bs0[f], acc[j][f], 0,0,0);
                acc[j][f] = __builtin_amdgcn_mfma_f32_16x16x32_bf16(A[j][1], Bs1[f], acc[j][f], 0,0,0);
            }

        // B half 1 (cog 4..7) + MFMA
        #pragma unroll
        for (int f = 0; f < 4; ++f) {
            Bs0[f] = *(const bf16x8*)(Wb2 + (size_t)(kk*16 +  4 + f) * 512 + lane * 8);
            Bs1[f] = *(const bf16x8*)(Wb2 + (size_t)(kk*16 + 12 + f) * 512 + lane * 8);
        }
        #pragma unroll
        for (int j = 0; j < 2; ++j)
            #pragma unroll
            for (int f = 0; f < 4; ++f) {
                acc[j][4+f] = __builtin_amdgcn_mfma_f32_16x16x32_bf16(A[j][0], Bs0[f], acc[j][4+f], 0,0,0);
                acc[j][4+f] = __builtin_amdgcn_mfma_f32_16x16x32_bf16(A[j][1], Bs1[f], acc[j][4+f], 0,0,0);
            }
    }

    // ---- epilogue: acc -> LDS [co][px pitch 260] -> coalesced stores ----
    __syncthreads();   // all waves done reading window/Dt; safe to overlay epi
    #pragma unroll
    for (int j = 0; j < 2; ++j)
        #pragma unroll
        for (int fn = 0; fn < 8; ++fn)
            *(f32x4*)(epi + (size_t)(16*fn + l15) * 260 + 32*wv + 16*j + 4*l4) = acc[j][fn];
    __syncthreads();

    float* ob = out + (size_t)b * COUTC * HWC + h0 * 128;
    #pragma unroll
    for (int it = 0; it < 16; ++it) {
        int idx = it * 512 + tid;
        int o = idx >> 6, c = idx & 63;
        f32x4 v = *(const f32x4*)(epi + (size_t)o * 260 + 4*c);
        *(f32x4*)(ob + (size_t)o * HWC + 4*c) = v;
    }
}

extern "C" void kernel_launch(void* const* d_in, const int* in_sizes, int n_in,
                              void* d_out, int out_size, void* d_ws, size_t ws_size,
                              hipStream_t stream)
{
    const float* x     = (const float*)d_in[0];
    const float* pre_w = (const float*)d_in[1];
    const float* pre_b = (const float*)d_in[2];
    const float* off_w = (const float*)d_in[3];
    const float* off_b = (const float*)d_in[4];
    const float* mod_w = (const float*)d_in[5];
    const float* mod_b = (const float*)d_in[6];
    const float* reg_w = (const float*)d_in[7];
    float* out = (float*)d_out;

    unsigned short* xp  = (unsigned short*)d_ws;                             // 16,777,216 B
    unsigned short* Wb2 = (unsigned short*)((char*)d_ws + 16777216);         //    147,456 B
    unsigned short* Wc2 = (unsigned short*)((char*)d_ws + 16924672);         //     36,864 B

    prep_conv<<<dim3(872), dim3(256), 0, stream>>>(x, pre_w, pre_b, off_w, mod_w,
                                                   reg_w, xp, Wb2, Wc2);
    gather_einsum<<<dim3(512), dim3(512), 0, stream>>>(xp, Wb2, Wc2, off_b, mod_b, out);
}